// Round 2
// 586.154 us; speedup vs baseline: 1.0252x; 1.0252x over previous
//
#include <hip/hip_runtime.h>
#include <hip/hip_bf16.h>
#include <stdint.h>

typedef __attribute__((ext_vector_type(8))) short bf16x8;
typedef __attribute__((ext_vector_type(4))) float f32x4;

__device__ __forceinline__ unsigned short f2bf(float f) {
    union { float f; unsigned int u; } v; v.f = f;
    unsigned int u = v.u;
    u += 0x7fffu + ((u >> 16) & 1u);   // round-to-nearest-even
    return (unsigned short)(u >> 16);
}

// Pack the 5 fp32 [128,128] weight mats into one bf16 [640,128] array in ws.
// Row order: [0,128)=a_g  [128,256)=a_p  [256,384)=b_g  [384,512)=b_p  [512,640)=g
__global__ __launch_bounds__(256) void prep_w(
    const float* __restrict__ apw, const float* __restrict__ agw,
    const float* __restrict__ bpw, const float* __restrict__ bgw,
    const float* __restrict__ gw, unsigned short* __restrict__ W)
{
    int idx = blockIdx.x * 256 + threadIdx.x;   // 0 .. 81919
    int o = idx >> 7;
    int k = idx & 127;
    const float* src; int oo;
    if (o < 128)      { src = agw; oo = o;       }
    else if (o < 256) { src = apw; oo = o - 128; }
    else if (o < 384) { src = bgw; oo = o - 256; }
    else if (o < 512) { src = bpw; oo = o - 384; }
    else              { src = gw;  oo = o - 512; }
    W[idx] = f2bf(src[oo * 128 + k]);
}

// Fused: LayerNorm -> {a = mask*sigmoid(z@ag^T+agb)*(z@ap^T+apb),
//                      b = likewise, g = sigmoid(z@gw^T+gb)}
// One block = 64 rows. 4 waves: w0/w1 -> a (hidden tiles 0-3 / 4-7),
// w2/w3 -> b; g hidden tiles split 2 per wave.
//
// MFMA operands SWAPPED vs original: mfma(W_frag, z_frag, acc).
// A/B fragments share the same lane layout, so the same loaded data serves
// both roles; D is transposed: col(lane&15)=z-row, row(quad*4+rg)=channel.
// => each lane's 4 acc regs are 4 CONTIGUOUS channels of one row
// => one float4 nontemporal store per tile instead of 4 scalar stores,
//    broadcast mask value, contiguous float4 bias loads.
__global__ __launch_bounds__(256) void fused_tri(
    const float* __restrict__ x, const float* __restrict__ mask,
    const float* __restrict__ lnw, const float* __restrict__ lnb,
    const float* __restrict__ apb, const float* __restrict__ agb,
    const float* __restrict__ bpb, const float* __restrict__ bgb,
    const float* __restrict__ gbb,
    const unsigned short* __restrict__ W,
    float* __restrict__ outA, float* __restrict__ outB, float* __restrict__ outG)
{
    __shared__ unsigned short z[64][136];   // +8 bf16 pad: 2-way LDS conflicts only (free)
    __shared__ float mlds[64];
    const int tid = threadIdx.x;
    const long rowbase = (long)blockIdx.x * 64;

    // ---- Phase 1: LayerNorm (4 threads per row, 32 ch each) ----
    {
        const int r = tid >> 2;
        const int part = tid & 3;
        const float4* xv = (const float4*)(x + (rowbase + r) * 128 + part * 32);
        float4 v[8];
#pragma unroll
        for (int i = 0; i < 8; i++) v[i] = xv[i];
        float s = 0.f, sq = 0.f;
#pragma unroll
        for (int i = 0; i < 8; i++) {
            s  += (v[i].x + v[i].y) + (v[i].z + v[i].w);
            sq += (v[i].x * v[i].x + v[i].y * v[i].y) + (v[i].z * v[i].z + v[i].w * v[i].w);
        }
        s  += __shfl_xor(s, 1);  sq += __shfl_xor(sq, 1);
        s  += __shfl_xor(s, 2);  sq += __shfl_xor(sq, 2);
        const float mu = s * 0.0078125f;
        const float var = sq * 0.0078125f - mu * mu;
        const float rs = rsqrtf(var + 1e-5f);
        const float4* wv = (const float4*)(lnw + part * 32);
        const float4* bv = (const float4*)(lnb + part * 32);
        unsigned short* zp = &z[r][part * 32];
#pragma unroll
        for (int i = 0; i < 8; i++) {
            const float4 wc = wv[i], bc = bv[i];
            const unsigned int lo = (unsigned)f2bf((v[i].x - mu) * rs * wc.x + bc.x)
                                  | ((unsigned)f2bf((v[i].y - mu) * rs * wc.y + bc.y) << 16);
            const unsigned int hi = (unsigned)f2bf((v[i].z - mu) * rs * wc.z + bc.z)
                                  | ((unsigned)f2bf((v[i].w - mu) * rs * wc.w + bc.w) << 16);
            *(uint2*)&zp[i * 4] = make_uint2(lo, hi);
        }
        if (tid < 64) mlds[tid] = mask[rowbase + tid];
    }
    __syncthreads();

    // ---- Phase 2: MFMA (16x16x32 bf16), swapped operands ----
    const int lane = tid & 63;
    const int wid  = tid >> 6;
    const int m16  = lane & 15;   // z-row within 16-row tile (D col)
    const int quad = lane >> 4;   // k-chunk selector / channel-group (D row / 4)

    bf16x8 afrag[4][4];           // z fragments [row-tile][k-chunk]; 64 VGPRs
#pragma unroll
    for (int rt = 0; rt < 4; rt++)
#pragma unroll
        for (int kk = 0; kk < 4; kk++)
            afrag[rt][kk] = *(const bf16x8*)&z[rt * 16 + m16][kk * 32 + quad * 8];

    // mask broadcast per row-tile (one value covers all 4 channels of the lane)
    float mv[4];
#pragma unroll
    for (int rt = 0; rt < 4; rt++) mv[rt] = mlds[rt * 16 + m16];

    // a/b gated jobs
    {
        const int ab    = wid >> 1;          // 0 -> a, 1 -> b
        const int hbase = (wid & 1) * 4;     // hidden tiles 0-3 or 4-7
        const float* gbias = ab ? bgb : agb;
        const float* pbias = ab ? bpb : apb;
        float* outp = ab ? outB : outA;
        const int wbase = ab ? 256 : 0;
#pragma unroll
        for (int h = hbase; h < hbase + 4; h++) {
            const unsigned short* wg = W + (size_t)(wbase + h * 16 + m16) * 128 + quad * 8;
            const unsigned short* wp = wg + 128 * 128;   // proj mat is +128 rows
            bf16x8 bg[4], bp[4];
#pragma unroll
            for (int kk = 0; kk < 4; kk++) {
                bg[kk] = *(const bf16x8*)(wg + kk * 32);
                bp[kk] = *(const bf16x8*)(wp + kk * 32);
            }
            const float4 bg4 = *(const float4*)(gbias + h * 16 + quad * 4);
            const float4 bp4 = *(const float4*)(pbias + h * 16 + quad * 4);
#pragma unroll
            for (int rt = 0; rt < 4; rt++) {
                f32x4 accg = {0.f, 0.f, 0.f, 0.f};
                f32x4 accp = {0.f, 0.f, 0.f, 0.f};
#pragma unroll
                for (int kk = 0; kk < 4; kk++) {
                    accg = __builtin_amdgcn_mfma_f32_16x16x32_bf16(bg[kk], afrag[rt][kk], accg, 0, 0, 0);
                    accp = __builtin_amdgcn_mfma_f32_16x16x32_bf16(bp[kk], afrag[rt][kk], accp, 0, 0, 0);
                }
                const int rloc = rt * 16 + m16;
                const float mval = mv[rt];
                f32x4 res;
                {
                    const float gv0 = accg[0] + bg4.x, pv0 = accp[0] + bp4.x;
                    const float gv1 = accg[1] + bg4.y, pv1 = accp[1] + bp4.y;
                    const float gv2 = accg[2] + bg4.z, pv2 = accp[2] + bp4.z;
                    const float gv3 = accg[3] + bg4.w, pv3 = accp[3] + bp4.w;
                    res[0] = mval * (1.f / (1.f + __expf(-gv0))) * pv0;
                    res[1] = mval * (1.f / (1.f + __expf(-gv1))) * pv1;
                    res[2] = mval * (1.f / (1.f + __expf(-gv2))) * pv2;
                    res[3] = mval * (1.f / (1.f + __expf(-gv3))) * pv3;
                }
                f32x4* dst = (f32x4*)(outp + (rowbase + rloc) * 128 + h * 16 + quad * 4);
                __builtin_nontemporal_store(res, dst);
            }
        }
    }
    // g jobs: 2 hidden tiles per wave
    {
#pragma unroll
        for (int h = wid * 2; h < wid * 2 + 2; h++) {
            const unsigned short* wq = W + (size_t)(512 + h * 16 + m16) * 128 + quad * 8;
            bf16x8 bq[4];
#pragma unroll
            for (int kk = 0; kk < 4; kk++) bq[kk] = *(const bf16x8*)(wq + kk * 32);
            const float4 b4 = *(const float4*)(gbb + h * 16 + quad * 4);
#pragma unroll
            for (int rt = 0; rt < 4; rt++) {
                f32x4 acc = {0.f, 0.f, 0.f, 0.f};
#pragma unroll
                for (int kk = 0; kk < 4; kk++)
                    acc = __builtin_amdgcn_mfma_f32_16x16x32_bf16(bq[kk], afrag[rt][kk], acc, 0, 0, 0);
                const int rloc = rt * 16 + m16;
                f32x4 res;
                res[0] = 1.f / (1.f + __expf(-(acc[0] + b4.x)));
                res[1] = 1.f / (1.f + __expf(-(acc[1] + b4.y)));
                res[2] = 1.f / (1.f + __expf(-(acc[2] + b4.z)));
                res[3] = 1.f / (1.f + __expf(-(acc[3] + b4.w)));
                f32x4* dst = (f32x4*)(outG + (rowbase + rloc) * 128 + h * 16 + quad * 4);
                __builtin_nontemporal_store(res, dst);
            }
        }
    }
}

extern "C" void kernel_launch(void* const* d_in, const int* in_sizes, int n_in,
                              void* d_out, int out_size, void* d_ws, size_t ws_size,
                              hipStream_t stream)
{
    const float* x    = (const float*)d_in[0];
    const float* mask = (const float*)d_in[1];
    const float* lnw  = (const float*)d_in[2];
    const float* lnb  = (const float*)d_in[3];
    const float* apw  = (const float*)d_in[4];
    const float* apb  = (const float*)d_in[5];
    const float* agw  = (const float*)d_in[6];
    const float* agb  = (const float*)d_in[7];
    const float* bpw  = (const float*)d_in[8];
    const float* bpb  = (const float*)d_in[9];
    const float* bgw  = (const float*)d_in[10];
    const float* bgb  = (const float*)d_in[11];
    const float* gw   = (const float*)d_in[12];
    const float* gbb  = (const float*)d_in[13];

    unsigned short* W = (unsigned short*)d_ws;     // 640*128 bf16 = 160 KB
    const long R = (long)in_sizes[0] / 128;        // 262144 (i,j) rows
    float* outA = (float*)d_out;
    float* outB = outA + R * 128;
    float* outG = outB + R * 128;

    prep_w<<<(640 * 128) / 256, 256, 0, stream>>>(apw, agw, bpw, bgw, gw, W);
    fused_tri<<<(int)(R / 64), 256, 0, stream>>>(x, mask, lnw, lnb,
                                                 apb, agb, bpb, bgb, gbb,
                                                 W, outA, outB, outG);
}